// Round 13
// baseline (287.031 us; speedup 1.0000x reference)
//
#include <hip/hip_runtime.h>

#define D 128
#define PCHUNK 4096
#define SCAP 8192

typedef short bf16x8 __attribute__((ext_vector_type(8)));
typedef float f32x4 __attribute__((ext_vector_type(4)));

__device__ __forceinline__ ushort f2b(float f){
  unsigned u = __builtin_bit_cast(unsigned, f);
  u += 0x7fffu + ((u >> 16) & 1u);          // round-to-nearest-even
  return (ushort)(u >> 16);
}
__device__ __forceinline__ float b2f(ushort h){
  unsigned u = ((unsigned)h) << 16;
  return __builtin_bit_cast(float, u);
}

// unpack 8 bf16, apply per-channel affine+relu, repack (channels cb..cb+7)
__device__ __forceinline__ int4 bnpack8(int4 v, float4 a0, float4 a1, float4 b0, float4 b1){
  unsigned w0=(unsigned)v.x, w1=(unsigned)v.y, w2=(unsigned)v.z, w3=(unsigned)v.w;
  float x0 = fmaxf(fmaf(a0.x, b2f((ushort)w0),        b0.x), 0.f);
  float x1 = fmaxf(fmaf(a0.y, b2f((ushort)(w0>>16)),  b0.y), 0.f);
  float x2 = fmaxf(fmaf(a0.z, b2f((ushort)w1),        b0.z), 0.f);
  float x3 = fmaxf(fmaf(a0.w, b2f((ushort)(w1>>16)),  b0.w), 0.f);
  float x4 = fmaxf(fmaf(a1.x, b2f((ushort)w2),        b1.x), 0.f);
  float x5 = fmaxf(fmaf(a1.y, b2f((ushort)(w2>>16)),  b1.y), 0.f);
  float x6 = fmaxf(fmaf(a1.z, b2f((ushort)w3),        b1.z), 0.f);
  float x7 = fmaxf(fmaf(a1.w, b2f((ushort)(w3>>16)),  b1.w), 0.f);
  int4 r;
  r.x = (int)((unsigned)f2b(x0) | ((unsigned)f2b(x1)<<16));
  r.y = (int)((unsigned)f2b(x2) | ((unsigned)f2b(x3)<<16));
  r.z = (int)((unsigned)f2b(x4) | ((unsigned)f2b(x5)<<16));
  r.w = (int)((unsigned)f2b(x6) | ((unsigned)f2b(x7)<<16));
  return r;
}

// ---------------- prep: weight transposes + dst histogram + x cast, ONE launch --------
// blocks [0,320): wt jobs; [320,1344): p0 histogram; [1344,3392): xcast grid-stride.
__global__ __launch_bounds__(256) void k_prep(
    const float* __restrict__ w_self1, const float* __restrict__ w_neigh1,
    const float* __restrict__ w_self2, const float* __restrict__ w_neigh2,
    const float* __restrict__ w_skip,
    ushort* __restrict__ Wb1, ushort* __restrict__ Wb2, ushort* __restrict__ Wb3,
    const int* __restrict__ dst, int* __restrict__ bcnt, int E,
    const float* __restrict__ x, ushort* __restrict__ xb, long long n4){
  __shared__ int h[512];
  const int bid = blockIdx.x;
  if (bid < 320){
    const int grp = bid >> 6;
    const int idx = (bid & 63)*256 + threadIdx.x;
    const int k = idx >> 7, c = idx & 127;
    const float* W; ushort* Wb; int K, k0;
    switch (grp){
      case 0: W=w_self1;  Wb=Wb1; K=256; k0=0;   break;
      case 1: W=w_neigh1; Wb=Wb1; K=256; k0=128; break;
      case 2: W=w_self2;  Wb=Wb2; K=256; k0=0;   break;
      case 3: W=w_neigh2; Wb=Wb2; K=256; k0=128; break;
      default:W=w_skip;   Wb=Wb3; K=128; k0=0;   break;
    }
    Wb[(size_t)c*K + k0 + k] = f2b(W[idx]);
  } else if (bid < 1344){
    const int pb = bid - 320;             // 0..1023
    for (int u=threadIdx.x; u<512; u+=256) h[u]=0;
    __syncthreads();
    for (long long i=(long long)pb*256+threadIdx.x; i<E; i+=(long long)1024*256)
      atomicAdd(&h[dst[i]>>8], 1);
    __syncthreads();
    for (int u=threadIdx.x; u<512; u+=256) if (h[u]) atomicAdd(&bcnt[u], h[u]);
  } else {
    long long i = (long long)(bid-1344)*256 + threadIdx.x;
    const long long stride = 2048LL*256;
    for (; i < n4; i += stride){
      float4 v = reinterpret_cast<const float4*>(x)[i];
      ushort4 o;
      o.x = f2b(v.x); o.y = f2b(v.y); o.z = f2b(v.z); o.w = f2b(v.w);
      reinterpret_cast<ushort4*>(xb)[i] = o;
    }
  }
}

// ---------------- P1: scan buckets -> base & cursor ----------------
__global__ void k_bscan(const int* __restrict__ bcnt, int* __restrict__ bbase,
                        int* __restrict__ bcur, int nb, int E){
  __shared__ int sh[1024];
  int t = threadIdx.x;
  int v = (t<nb) ? bcnt[t] : 0;
  sh[t]=v; __syncthreads();
  for (int off=1; off<1024; off<<=1){
    int add = (t>=off)?sh[t-off]:0;
    __syncthreads();
    sh[t]+=add;
    __syncthreads();
  }
  if (t<nb){ int e=sh[t]-v; bbase[t]=e; bcur[t]=e; }
  if (t==nb) bbase[t]=E;
}

// ---------------- P2: LDS-binned partition; pairs packed as src | (dst&255)<<24 ------
__global__ __launch_bounds__(256) void k_part(const int* __restrict__ src,
        const int* __restrict__ dst, int* __restrict__ bcur,
        unsigned* __restrict__ pairs, int E){
  __shared__ int hist[512], offA[512], offB[512], gbase[512];
  __shared__ int sS[PCHUNK], sD[PCHUNK];
  const int t = threadIdx.x;
  const int base = blockIdx.x * PCHUNK;
  const int cnt = min(PCHUNK, E - base);
  for (int u=t; u<512; u+=256) hist[u]=0;
  __syncthreads();
  int rs[16], rd[16];
  #pragma unroll
  for (int j=0;j<16;j++){
    int li = j*256 + t;
    if (li < cnt){
      rs[j]=src[base+li]; rd[j]=dst[base+li];
      atomicAdd(&hist[rd[j]>>8],1);
    } else { rs[j]=0; rd[j]=-1; }
  }
  __syncthreads();
  int *cur=offA, *nxt=offB;
  for (int u=t; u<512; u+=256) cur[u]=hist[u];
  __syncthreads();
  for (int off=1; off<512; off<<=1){
    for (int u=t; u<512; u+=256) nxt[u] = cur[u] + ((u>=off)?cur[u-off]:0);
    __syncthreads();
    int* tmp=cur; cur=nxt; nxt=tmp;
  }
  for (int u=t; u<512; u+=256) nxt[u] = cur[u]-hist[u];
  __syncthreads();
  #pragma unroll
  for (int j=0;j<16;j++){
    if (j*256+t < cnt){
      int b = rd[j]>>8;
      int p = atomicAdd(&nxt[b],1);
      sS[p]=rs[j]; sD[p]=rd[j];
    }
  }
  __syncthreads();
  for (int u=t; u<512; u+=256){
    int c = hist[u];
    if (c>0) gbase[u] = atomicAdd(&bcur[u], c);
  }
  __syncthreads();
  #pragma unroll
  for (int j=0;j<16;j++){
    int idx = j*256+t;
    if (idx<cnt){
      int d = sD[idx]; int b = d>>8;
      int gpos = gbase[b] + (idx - (cur[b]-hist[b]));
      pairs[gpos] = (unsigned)sS[idx] | ((unsigned)(d & 255) << 24);
    }
  }
}

// ---------------- P3: per-bucket exact counting sort -> slots + offs ----------------
__global__ __launch_bounds__(256) void k_sortb(const unsigned* __restrict__ pairs,
        const int* __restrict__ bbase, int* __restrict__ offs,
        int* __restrict__ slots, int N, int NB){
  __shared__ int nh[256], nc[256], sc[256];
  __shared__ int stage[SCAP];
  const int b = blockIdx.x, t = threadIdx.x;
  const int base = bbase[b];
  const int cnt  = bbase[b+1] - base;
  nh[t]=0; __syncthreads();
  for (int i=t;i<cnt;i+=256) atomicAdd(&nh[pairs[base+i] >> 24],1);
  __syncthreads();
  int v = nh[t];
  sc[t]=v; __syncthreads();
  for (int off=1; off<256; off<<=1){
    int add = (t>=off)?sc[t-off]:0;
    __syncthreads();
    sc[t]+=add;
    __syncthreads();
  }
  int excl = sc[t]-v;
  nc[t]=excl;
  int node = (b<<8)+t;
  if (node<N) offs[node]=base+excl;
  if (b==NB-1 && t==0) offs[N]=bbase[NB];
  __syncthreads();
  if (cnt<=SCAP){
    for (int i=t;i<cnt;i+=256){
      unsigned p = pairs[base+i];
      int pos = atomicAdd(&nc[p >> 24],1);
      stage[pos]=(int)(p & 0xffffffu);
    }
    __syncthreads();
    for (int i=t;i<cnt;i+=256) slots[base+i]=stage[i];
  } else {
    for (int i=t;i<cnt;i+=256){
      unsigned p = pairs[base+i];
      int pos = atomicAdd(&nc[p >> 24],1);
      slots[base+pos]=(int)(p & 0xffffffu);
    }
  }
}

// ---------------- gather-mean, optional inline BN+ReLU of the gathered rows -----------
// BN=false: mean of raw bf16 rows (layer 1). BN=true: mean of relu(a*x+b) where (a,b)
// are the layer-1 BN affine per channel (computed per-lane from sum/sq) -> eliminates
// the separate BN+ReLU pass; reads h1pre directly.
template<bool BN>
__global__ __launch_bounds__(256) void k_gatherb(const ushort* __restrict__ Xb,
        const int* __restrict__ slots, const int* __restrict__ offs,
        ushort* __restrict__ meanb, int N,
        const float* __restrict__ sum, const float* __restrict__ sq,
        const float* __restrict__ g, const float* __restrict__ be, float invN){
  int node = blockIdx.x*4 + (threadIdx.x >> 6);
  int c2 = (threadIdx.x & 63) * 2;            // this lane's channel pair
  if (node >= N) return;
  float a0=0.f,a1=0.f,b0c=0.f,b1c=0.f;
  if (BN){
    float m0 = sum[c2]*invN,   m1 = sum[c2+1]*invN;
    float v0 = sq[c2]*invN - m0*m0, v1 = sq[c2+1]*invN - m1*m1;
    a0 = g[c2]  *rsqrtf(fmaxf(v0,0.f)+1e-5f);
    a1 = g[c2+1]*rsqrtf(fmaxf(v1,0.f)+1e-5f);
    b0c = be[c2]   - m0*a0;
    b1c = be[c2+1] - m1*a1;
  }
#define AX0(x) (BN ? fmaxf(fmaf(a0,(x),b0c),0.f) : (x))
#define AX1(x) (BN ? fmaxf(fmaf(a1,(x),b1c),0.f) : (x))
  const int beg = offs[node], end = offs[node+1];
  float sx0=0,sy0=0,sx1=0,sy1=0,sx2=0,sy2=0,sx3=0,sy3=0;
  int j = beg;
  while (j < end && (j & 3)){
    unsigned u = *reinterpret_cast<const unsigned*>(&Xb[(size_t)slots[j]*D + c2]);
    sx0 += AX0(b2f((ushort)u)); sy0 += AX1(b2f((ushort)(u>>16)));
    ++j;
  }
  const int nfull = (end - j) >> 2;
  const int4* sp = reinterpret_cast<const int4*>(slots + j);

#define G8(ia, ib) { \
    unsigned u0 = *reinterpret_cast<const unsigned*>(&Xb[(size_t)(ia).x*D + c2]); \
    unsigned u1 = *reinterpret_cast<const unsigned*>(&Xb[(size_t)(ia).y*D + c2]); \
    unsigned u2 = *reinterpret_cast<const unsigned*>(&Xb[(size_t)(ia).z*D + c2]); \
    unsigned u3 = *reinterpret_cast<const unsigned*>(&Xb[(size_t)(ia).w*D + c2]); \
    unsigned u4 = *reinterpret_cast<const unsigned*>(&Xb[(size_t)(ib).x*D + c2]); \
    unsigned u5 = *reinterpret_cast<const unsigned*>(&Xb[(size_t)(ib).y*D + c2]); \
    unsigned u6 = *reinterpret_cast<const unsigned*>(&Xb[(size_t)(ib).z*D + c2]); \
    unsigned u7 = *reinterpret_cast<const unsigned*>(&Xb[(size_t)(ib).w*D + c2]); \
    sx0 += AX0(b2f((ushort)u0)); sy0 += AX1(b2f((ushort)(u0>>16))); \
    sx1 += AX0(b2f((ushort)u1)); sy1 += AX1(b2f((ushort)(u1>>16))); \
    sx2 += AX0(b2f((ushort)u2)); sy2 += AX1(b2f((ushort)(u2>>16))); \
    sx3 += AX0(b2f((ushort)u3)); sy3 += AX1(b2f((ushort)(u3>>16))); \
    sx0 += AX0(b2f((ushort)u4)); sy0 += AX1(b2f((ushort)(u4>>16))); \
    sx1 += AX0(b2f((ushort)u5)); sy1 += AX1(b2f((ushort)(u5>>16))); \
    sx2 += AX0(b2f((ushort)u6)); sy2 += AX1(b2f((ushort)(u6>>16))); \
    sx3 += AX0(b2f((ushort)u7)); sy3 += AX1(b2f((ushort)(u7>>16))); }

  int g8 = 0;
  if (nfull >= 2){
    int4 ia = sp[0], ib = sp[1];
    for (g8 = 2; g8 + 2 <= nfull; g8 += 2){
      int4 na = sp[g8], nb = sp[g8+1];
      G8(ia, ib);
      ia = na; ib = nb;
    }
    G8(ia, ib);
  }
  if (g8 < nfull){
    int4 ia = sp[g8];
    unsigned u0 = *reinterpret_cast<const unsigned*>(&Xb[(size_t)ia.x*D + c2]);
    unsigned u1 = *reinterpret_cast<const unsigned*>(&Xb[(size_t)ia.y*D + c2]);
    unsigned u2 = *reinterpret_cast<const unsigned*>(&Xb[(size_t)ia.z*D + c2]);
    unsigned u3 = *reinterpret_cast<const unsigned*>(&Xb[(size_t)ia.w*D + c2]);
    sx0 += AX0(b2f((ushort)u0)); sy0 += AX1(b2f((ushort)(u0>>16)));
    sx1 += AX0(b2f((ushort)u1)); sy1 += AX1(b2f((ushort)(u1>>16)));
    sx2 += AX0(b2f((ushort)u2)); sy2 += AX1(b2f((ushort)(u2>>16)));
    sx3 += AX0(b2f((ushort)u3)); sy3 += AX1(b2f((ushort)(u3>>16)));
  }
  j += 4*nfull;
  for (; j < end; ++j){
    unsigned u = *reinterpret_cast<const unsigned*>(&Xb[(size_t)slots[j]*D + c2]);
    sx0 += AX0(b2f((ushort)u)); sy0 += AX1(b2f((ushort)(u>>16)));
  }
#undef G8
#undef AX0
#undef AX1
  float deg = (float)(end - beg);
  float rc = deg > 0.f ? 1.0f/deg : 0.f;
  unsigned o = (unsigned)f2b((sx0+sx1+sx2+sx3)*rc)
             | ((unsigned)f2b((sy0+sy1+sy2+sy3)*rc) << 16);
  *reinterpret_cast<unsigned*>(&meanb[(size_t)node*D + c2]) = o;
}

// ---------------- W-resident persistent MFMA GEMM: 128x128 tile, 64x64 waves ----------
// All of W (and Wk) staged into LDS once per persistent block. Per k-step staging is
// A-only; 4-deep A register lookahead; raw s_barrier (lgkmcnt only); setprio on MFMA.
// SKIP=true (layer 2) additionally applies the layer-1 BN+ReLU affine to the SELF half
// (k-steps 0..3) during A-staging — A0 = h1pre, coefficients from sumA/sqA via LDS table.
template<bool SKIP>
__global__ __launch_bounds__(256, 1) void k_mfma(
    const ushort* __restrict__ A0, const ushort* __restrict__ A1,
    const ushort* __restrict__ Wb, const ushort* __restrict__ Wk,
    const float* __restrict__ bias, const float* __restrict__ biasK,
    ushort* __restrict__ C, ushort* __restrict__ Ck,
    float* __restrict__ gS, float* __restrict__ gQ,
    float* __restrict__ gSK, float* __restrict__ gQK, int N, int NT,
    const float* __restrict__ sumA, const float* __restrict__ sqA,
    const float* __restrict__ gA, const float* __restrict__ beA, float invN)
{
  __shared__ ushort Wt8[8][128][40];
  __shared__ ushort Wkt4[SKIP ? 4*128*40 : 1];
  __shared__ ushort At[2][128][40];
  __shared__ float shS[128], shQ[128], shSK[SKIP?128:1], shQK[SKIP?128:1];
  __shared__ float Af[SKIP?128:1], Bf[SKIP?128:1];
  const int tid = threadIdx.x;
  if (tid < 128){ shS[tid]=0.f; shQ[tid]=0.f; if (SKIP){ shSK[tid]=0.f; shQK[tid]=0.f; } }
  const int bid = blockIdx.x, gridN = gridDim.x;
  const int lane = tid & 63, wid = tid >> 6;
  const int wr = wid >> 1, wc = wid & 1;
  const int lr = lane & 15, kq = lane >> 4;
  const int sr4 = tid >> 2, s8 = (tid & 3) * 8;   // staging rows sr4 and sr4+64

  if (SKIP && tid < 128){
    float m = sumA[tid]*invN;
    float v = sqA[tid]*invN - m*m;
    float a = gA[tid]*rsqrtf(fmaxf(v,0.f)+1e-5f);
    Af[tid] = a;
    Bf[tid] = beA[tid] - m*a;
  }

  // ---- W prologue: stage all weight slices once ----
  #pragma unroll
  for (int s=0;s<8;s++){
    *reinterpret_cast<int4*>(&Wt8[s][sr4][s8]) =
        *reinterpret_cast<const int4*>(&Wb[(size_t)sr4*256 + s*32 + s8]);
    *reinterpret_cast<int4*>(&Wt8[s][sr4+64][s8]) =
        *reinterpret_cast<const int4*>(&Wb[(size_t)(sr4+64)*256 + s*32 + s8]);
  }
  if (SKIP){
    #pragma unroll
    for (int s=0;s<4;s++){
      *reinterpret_cast<int4*>(&Wkt4[((s*128) + sr4)*40 + s8]) =
          *reinterpret_cast<const int4*>(&Wk[(size_t)sr4*128 + s*32 + s8]);
      *reinterpret_cast<int4*>(&Wkt4[((s*128) + sr4 + 64)*40 + s8]) =
          *reinterpret_cast<const int4*>(&Wk[(size_t)(sr4+64)*128 + s*32 + s8]);
    }
  }

  // 4 named A load-sets, 2 int4 each (rows sr4, sr4+64)
  int4 va0a,va0b, va1a,va1b, va2a,va2b, va3a,va3b;

#define LOADA(S, GT, TT) { \
    int gr0_ = (GT)*128 + sr4;      if (gr0_ >= N) gr0_ = N-1; \
    int gr1_ = (GT)*128 + sr4 + 64; if (gr1_ >= N) gr1_ = N-1; \
    const ushort* As_ = ((TT) >= 4) ? A1 : A0; \
    const int ka_ = ((TT) & 3) * 32; \
    va##S##a = *reinterpret_cast<const int4*>(&As_[(size_t)gr0_*D + ka_ + s8]); \
    va##S##b = *reinterpret_cast<const int4*>(&As_[(size_t)gr1_*D + ka_ + s8]); }

#define WRITEA(S, BW, TT) { \
    int4 wa_ = va##S##a, wb_ = va##S##b; \
    if (SKIP && (TT) < 4){ \
      const int cb_ = ((TT)&3)*32 + s8; \
      float4 fa0_ = *reinterpret_cast<const float4*>(&Af[cb_]); \
      float4 fa1_ = *reinterpret_cast<const float4*>(&Af[cb_+4]); \
      float4 fb0_ = *reinterpret_cast<const float4*>(&Bf[cb_]); \
      float4 fb1_ = *reinterpret_cast<const float4*>(&Bf[cb_+4]); \
      wa_ = bnpack8(wa_, fa0_, fa1_, fb0_, fb1_); \
      wb_ = bnpack8(wb_, fa0_, fa1_, fb0_, fb1_); \
    } \
    *reinterpret_cast<int4*>(&At[BW][sr4][s8]) = wa_; \
    *reinterpret_cast<int4*>(&At[BW][sr4+64][s8]) = wb_; }

#define PBAR() { asm volatile("s_waitcnt lgkmcnt(0)" ::: "memory"); \
    __builtin_amdgcn_s_barrier(); __builtin_amdgcn_sched_barrier(0); }

#define STEPBODY(BR, TT, WITHK, ...) { \
    bf16x8 af0 = *reinterpret_cast<const bf16x8*>(&At[BR][64*wr + lr][kq*8]); \
    bf16x8 af1 = *reinterpret_cast<const bf16x8*>(&At[BR][64*wr + 16 + lr][kq*8]); \
    bf16x8 af2 = *reinterpret_cast<const bf16x8*>(&At[BR][64*wr + 32 + lr][kq*8]); \
    bf16x8 af3 = *reinterpret_cast<const bf16x8*>(&At[BR][64*wr + 48 + lr][kq*8]); \
    bf16x8 bw0 = *reinterpret_cast<const bf16x8*>(&Wt8[TT][64*wc + lr][kq*8]); \
    bf16x8 bw1 = *reinterpret_cast<const bf16x8*>(&Wt8[TT][64*wc + 16 + lr][kq*8]); \
    bf16x8 bw2 = *reinterpret_cast<const bf16x8*>(&Wt8[TT][64*wc + 32 + lr][kq*8]); \
    bf16x8 bw3 = *reinterpret_cast<const bf16x8*>(&Wt8[TT][64*wc + 48 + lr][kq*8]); \
    bf16x8 bk0{}, bk1{}, bk2{}, bk3{}; \
    if (SKIP && (WITHK)){ \
      bk0 = *reinterpret_cast<const bf16x8*>(&Wkt4[(((TT)&3)*128 + 64*wc + lr)*40 + kq*8]); \
      bk1 = *reinterpret_cast<const bf16x8*>(&Wkt4[(((TT)&3)*128 + 64*wc + 16 + lr)*40 + kq*8]); \
      bk2 = *reinterpret_cast<const bf16x8*>(&Wkt4[(((TT)&3)*128 + 64*wc + 32 + lr)*40 + kq*8]); \
      bk3 = *reinterpret_cast<const bf16x8*>(&Wkt4[(((TT)&3)*128 + 64*wc + 48 + lr)*40 + kq*8]); \
    } \
    __VA_ARGS__; \
    __builtin_amdgcn_s_setprio(1); \
    acc[0][0] = __builtin_amdgcn_mfma_f32_16x16x32_bf16(af0, bw0, acc[0][0], 0,0,0); \
    acc[0][1] = __builtin_amdgcn_mfma_f32_16x16x32_bf16(af0, bw1, acc[0][1], 0,0,0); \
    acc[0][2] = __builtin_amdgcn_mfma_f32_16x16x32_bf16(af0, bw2, acc[0][2], 0,0,0); \
    acc[0][3] = __builtin_amdgcn_mfma_f32_16x16x32_bf16(af0, bw3, acc[0][3], 0,0,0); \
    acc[1][0] = __builtin_amdgcn_mfma_f32_16x16x32_bf16(af1, bw0, acc[1][0], 0,0,0); \
    acc[1][1] = __builtin_amdgcn_mfma_f32_16x16x32_bf16(af1, bw1, acc[1][1], 0,0,0); \
    acc[1][2] = __builtin_amdgcn_mfma_f32_16x16x32_bf16(af1, bw2, acc[1][2], 0,0,0); \
    acc[1][3] = __builtin_amdgcn_mfma_f32_16x16x32_bf16(af1, bw3, acc[1][3], 0,0,0); \
    acc[2][0] = __builtin_amdgcn_mfma_f32_16x16x32_bf16(af2, bw0, acc[2][0], 0,0,0); \
    acc[2][1] = __builtin_amdgcn_mfma_f32_16x16x32_bf16(af2, bw1, acc[2][1], 0,0,0); \
    acc[2][2] = __builtin_amdgcn_mfma_f32_16x16x32_bf16(af2, bw2, acc[2][2], 0,0,0); \
    acc[2][3] = __builtin_amdgcn_mfma_f32_16x16x32_bf16(af2, bw3, acc[2][3], 0,0,0); \
    acc[3][0] = __builtin_amdgcn_mfma_f32_16x16x32_bf16(af3, bw0, acc[3][0], 0,0,0); \
    acc[3][1] = __builtin_amdgcn_mfma_f32_16x16x32_bf16(af3, bw1, acc[3][1], 0,0,0); \
    acc[3][2] = __builtin_amdgcn_mfma_f32_16x16x32_bf16(af3, bw2, acc[3][2], 0,0,0); \
    acc[3][3] = __builtin_amdgcn_mfma_f32_16x16x32_bf16(af3, bw3, acc[3][3], 0,0,0); \
    if (SKIP && (WITHK)){ \
      accK[0][0] = __builtin_amdgcn_mfma_f32_16x16x32_bf16(af0, bk0, accK[0][0], 0,0,0); \
      accK[0][1] = __builtin_amdgcn_mfma_f32_16x16x32_bf16(af0, bk1, accK[0][1], 0,0,0); \
      accK[0][2] = __builtin_amdgcn_mfma_f32_16x16x32_bf16(af0, bk2, accK[0][2], 0,0,0); \
      accK[0][3] = __builtin_amdgcn_mfma_f32_16x16x32_bf16(af0, bk3, accK[0][3], 0,0,0); \
      accK[1][0] = __builtin_amdgcn_mfma_f32_16x16x32_bf16(af1, bk0, accK[1][0], 0,0,0); \
      accK[1][1] = __builtin_amdgcn_mfma_f32_16x16x32_bf16(af1, bk1, accK[1][1], 0,0,0); \
      accK[1][2] = __builtin_amdgcn_mfma_f32_16x16x32_bf16(af1, bk2, accK[1][2], 0,0,0); \
      accK[1][3] = __builtin_amdgcn_mfma_f32_16x16x32_bf16(af1, bk3, accK[1][3], 0,0,0); \
      accK[2][0] = __builtin_amdgcn_mfma_f32_16x16x32_bf16(af2, bk0, accK[2][0], 0,0,0); \
      accK[2][1] = __builtin_amdgcn_mfma_f32_16x16x32_bf16(af2, bk1, accK[2][1], 0,0,0); \
      accK[2][2] = __builtin_amdgcn_mfma_f32_16x16x32_bf16(af2, bk2, accK[2][2], 0,0,0); \
      accK[2][3] = __builtin_amdgcn_mfma_f32_16x16x32_bf16(af2, bk3, accK[2][3], 0,0,0); \
      accK[3][0] = __builtin_amdgcn_mfma_f32_16x16x32_bf16(af3, bk0, accK[3][0], 0,0,0); \
      accK[3][1] = __builtin_amdgcn_mfma_f32_16x16x32_bf16(af3, bk1, accK[3][1], 0,0,0); \
      accK[3][2] = __builtin_amdgcn_mfma_f32_16x16x32_bf16(af3, bk2, accK[3][2], 0,0,0); \
      accK[3][3] = __builtin_amdgcn_mfma_f32_16x16x32_bf16(af3, bk3, accK[3][3], 0,0,0); \
    } \
    __builtin_amdgcn_s_setprio(0); }

  f32x4 acc[4][4], accK[SKIP?4:1][SKIP?4:1];
  #pragma unroll
  for (int m=0;m<4;m++)
    #pragma unroll
    for (int n=0;n<4;n++){
      acc[m][n] = (f32x4){0.f,0.f,0.f,0.f};
      if (SKIP) accK[m][n] = (f32x4){0.f,0.f,0.f,0.f};
    }
  float bs[4]={0,0,0,0}, bq[4]={0,0,0,0}, bsk[4]={0,0,0,0}, bqk[4]={0,0,0,0};
  float bv[4], bkv[4];
  #pragma unroll
  for (int n=0;n<4;n++){
    bv[n] = bias[64*wc + 16*n + lr];
    bkv[n] = SKIP ? biasK[64*wc + 16*n + lr] : 0.f;
  }

  // barrier: Af/Bf + W staging visible before first WRITEA/use
  PBAR();

  // A prologue: prime 4 sets (k-steps 0..3 of first tile), stage step 0 into buf0
  {
    const int t0 = bid;
    LOADA(0, t0, 0);
    LOADA(1, t0, 1);
    LOADA(2, t0, 2);
    LOADA(3, t0, 3);
    WRITEA(0, 0, 0);
    PBAR();
  }

  for (int tile = bid; tile < NT; tile += gridN){
    const int tnext = tile + gridN;
    const bool hasnext = (tnext < NT);
    STEPBODY(0, 0, 1, LOADA(0, tile, 4));
    WRITEA(1, 1, 1); PBAR();
    STEPBODY(1, 1, 1, LOADA(1, tile, 5));
    WRITEA(2, 0, 2); PBAR();
    STEPBODY(0, 2, 1, LOADA(2, tile, 6));
    WRITEA(3, 1, 3); PBAR();
    STEPBODY(1, 3, 1, LOADA(3, tile, 7));
    WRITEA(0, 0, 4); PBAR();
    STEPBODY(0, 4, 0, if (hasnext) LOADA(0, tnext, 0));
    WRITEA(1, 1, 5); PBAR();
    STEPBODY(1, 5, 0, if (hasnext) LOADA(1, tnext, 1));
    WRITEA(2, 0, 6); PBAR();
    STEPBODY(0, 6, 0, if (hasnext) LOADA(2, tnext, 2));
    WRITEA(3, 1, 7); PBAR();
    STEPBODY(1, 7, 0, if (hasnext) LOADA(3, tnext, 3));
    if (hasnext){ WRITEA(0, 0, 0); PBAR(); }

    // per-tile epilogue (stores overlap next tile's in-flight loads / ds_reads)
    #pragma unroll
    for (int m=0;m<4;m++){
      #pragma unroll
      for (int r=0;r<4;r++){
        int row = tile*128 + 64*wr + 16*m + kq*4 + r;
        if (row < N){
          #pragma unroll
          for (int n=0;n<4;n++){
            int col = 64*wc + 16*n + lr;
            float v = acc[m][n][r] + bv[n];
            C[(size_t)row*D + col] = f2b(v);
            bs[n] += v; bq[n] += v*v;
            if (SKIP){
              float u = accK[m][n][r] + bkv[n];
              Ck[(size_t)row*D + col] = f2b(u);
              bsk[n] += u; bqk[n] += u*u;
            }
          }
        }
      }
    }
    #pragma unroll
    for (int m=0;m<4;m++)
      #pragma unroll
      for (int n=0;n<4;n++){
        acc[m][n] = (f32x4){0.f,0.f,0.f,0.f};
        if (SKIP) accK[m][n] = (f32x4){0.f,0.f,0.f,0.f};
      }
  }
#undef LOADA
#undef WRITEA
#undef PBAR
#undef STEPBODY

  // one stat-reduction per block
  #pragma unroll
  for (int n=0;n<4;n++){
    float s = bs[n], q = bq[n];
    s += __shfl_xor(s,16); s += __shfl_xor(s,32);
    q += __shfl_xor(q,16); q += __shfl_xor(q,32);
    if (kq == 0){
      int col = 64*wc + 16*n + lr;
      atomicAdd(&shS[col], s);
      atomicAdd(&shQ[col], q);
    }
    if (SKIP){
      float sk = bsk[n], qk = bqk[n];
      sk += __shfl_xor(sk,16); sk += __shfl_xor(sk,32);
      qk += __shfl_xor(qk,16); qk += __shfl_xor(qk,32);
      if (kq == 0){
        int col = 64*wc + 16*n + lr;
        atomicAdd(&shSK[col], sk);
        atomicAdd(&shQK[col], qk);
      }
    }
  }
  __syncthreads();
  if (tid < 128){
    unsafeAtomicAdd(&gS[tid], shS[tid]);
    unsafeAtomicAdd(&gQ[tid], shQ[tid]);
    if (SKIP){
      unsafeAtomicAdd(&gSK[tid], shSK[tid]);
      unsafeAtomicAdd(&gQK[tid], shQK[tid]);
    }
  }
}

// ---------------- final: out = relu(bn2(h2) + bn3(skip)), f32 out (BN in-block) -------
__global__ __launch_bounds__(256) void k_final(const ushort* __restrict__ h2,
      const ushort* __restrict__ sk, float* __restrict__ out,
      const float* __restrict__ sum2, const float* __restrict__ sq2,
      const float* __restrict__ g2, const float* __restrict__ be2,
      const float* __restrict__ sum3, const float* __restrict__ sq3,
      const float* __restrict__ g3, const float* __restrict__ be3,
      float invN, long long n4){
  __shared__ float A2[128], B2[128], A3[128], B3[128];
  if (threadIdx.x < 128){
    int c = threadIdx.x;
    float m2 = sum2[c]*invN;
    float v2 = sq2[c]*invN - m2*m2;
    float a2 = g2[c]*rsqrtf(fmaxf(v2, 0.f) + 1e-5f);
    A2[c] = a2; B2[c] = be2[c] - m2*a2;
    float m3 = sum3[c]*invN;
    float v3 = sq3[c]*invN - m3*m3;
    float a3 = g3[c]*rsqrtf(fmaxf(v3, 0.f) + 1e-5f);
    A3[c] = a3; B3[c] = be3[c] - m3*a3;
  }
  __syncthreads();
  long long i = (long long)blockIdx.x*256 + threadIdx.x;
  const long long stride = (long long)gridDim.x*256;
  for (; i < n4; i += stride){
    int c = ((int)(i & 31)) << 2;
    float4 a2 = *reinterpret_cast<const float4*>(A2 + c);
    float4 b2 = *reinterpret_cast<const float4*>(B2 + c);
    float4 a3 = *reinterpret_cast<const float4*>(A3 + c);
    float4 b3 = *reinterpret_cast<const float4*>(B3 + c);
    ushort4 h = reinterpret_cast<const ushort4*>(h2)[i];
    ushort4 s = reinterpret_cast<const ushort4*>(sk)[i];
    float4 v;
    v.x = fmaxf(a2.x*b2f(h.x) + b2.x + a3.x*b2f(s.x) + b3.x, 0.f);
    v.y = fmaxf(a2.y*b2f(h.y) + b2.y + a3.y*b2f(s.y) + b3.y, 0.f);
    v.z = fmaxf(a2.z*b2f(h.z) + b2.z + a3.z*b2f(s.z) + b3.z, 0.f);
    v.w = fmaxf(a2.w*b2f(h.w) + b2.w + a3.w*b2f(s.w) + b3.w, 0.f);
    reinterpret_cast<float4*>(out)[i] = v;
  }
}

extern "C" void kernel_launch(void* const* d_in, const int* in_sizes, int n_in,
                              void* d_out, int out_size, void* d_ws, size_t ws_size,
                              hipStream_t stream) {
  const float* x        = (const float*)d_in[0];
  const int*   src      = (const int*)  d_in[1];
  const int*   dst      = (const int*)  d_in[2];
  const float* w_self1  = (const float*)d_in[3];
  const float* w_neigh1 = (const float*)d_in[4];
  const float* b1       = (const float*)d_in[5];
  const float* w_self2  = (const float*)d_in[6];
  const float* w_neigh2 = (const float*)d_in[7];
  const float* b2       = (const float*)d_in[8];
  const float* w_skip   = (const float*)d_in[9];
  const float* b_skip   = (const float*)d_in[10];
  const float* g1       = (const float*)d_in[11];
  const float* be1      = (const float*)d_in[12];
  const float* g2       = (const float*)d_in[13];
  const float* be2      = (const float*)d_in[14];
  const float* g3       = (const float*)d_in[15];
  const float* be3      = (const float*)d_in[16];
  (void)n_in; (void)ws_size;

  const int N = in_sizes[0] / D;
  const int E = in_sizes[1];
  const int NB = (N + 255) >> 8;
  float* out = (float*)d_out;

  // ---- workspace layout ----
  char* p = (char*)d_ws;
  const size_t nd2 = (((size_t)N * D * 2) + 255) / 256 * 256;   // bf16 [N][D]
  ushort* meanb  = (ushort*)p; p += nd2;
  ushort* h2pre  = (ushort*)p; p += nd2;     // layer-2 pre-BN output
  ushort* hpre_b = (ushort*)p; p += nd2;     // layer-1 pre-BN output (h1pre)
  ushort* skip_b = (ushort*)p; p += nd2;
  ushort* Wb1    = (ushort*)p; p += 256*128*2;
  ushort* Wb2    = (ushort*)p; p += 256*128*2;
  ushort* Wb3    = (ushort*)p; p += 128*128*2;
  int*    offs   = (int*)p;   p += (((size_t)(N+1)*4) + 255) / 256 * 256;
  int*    bcnt   = (int*)p;   p += 2304;
  float*  st     = (float*)p; p += 1536*sizeof(float);
  int*    bbase  = (int*)p;   p += 2304;
  int*    bcur   = (int*)p;   p += 2048;
  float *sum1=st,      *sq1=st+128,  *sum2=st+256, *sq2=st+384, *sum3=st+512, *sq3=st+640;

  // scratch in d_out (dead before k_final rewrites all of d_out)
  const size_t slpad = (((size_t)E*4) + 255) / 256 * 256;
  const size_t xbpad = (((size_t)N*D*2) + 255) / 256 * 256;
  int*      slots = (int*)d_out;
  ushort*   xb    = (ushort*)((char*)d_out + slpad);
  unsigned* pairs = (unsigned*)((char*)d_out + slpad + xbpad);

  hipMemsetAsync(bcnt, 0, 2304 + 1536*sizeof(float), stream);

  const long long n4 = (long long)N * D / 4;

  // --- prep: weight transposes + dst histogram + x cast, one launch ---
  k_prep<<<3392, 256, 0, stream>>>(w_self1, w_neigh1, w_self2, w_neigh2, w_skip,
                                   Wb1, Wb2, Wb3, dst, bcnt, E, x, xb, n4);

  // --- CSR build ---
  k_bscan<<<1, 1024, 0, stream>>>(bcnt, bbase, bcur, NB, E);
  k_part<<<(E + PCHUNK - 1)/PCHUNK, 256, 0, stream>>>(src, dst, bcur, pairs, E);
  k_sortb<<<NB, 256, 0, stream>>>(pairs, bbase, offs, slots, N, NB);

  const int gablocks = (N + 3) / 4;
  const int NT = (N + 127) / 128;
  const int gpersist = 256;                 // 1 persistent block per CU (142KB LDS)
  const float invN = 1.0f / (float)N;

  // --- layer 1 ---
  k_gatherb<false><<<gablocks, 256, 0, stream>>>(xb, slots, offs, meanb, N,
                                                 nullptr, nullptr, nullptr, nullptr, 0.f);
  k_mfma<false><<<gpersist, 256, 0, stream>>>(xb, meanb, Wb1, nullptr, b1, nullptr,
                                              hpre_b, nullptr, sum1, sq1, nullptr, nullptr,
                                              N, NT, nullptr, nullptr, nullptr, nullptr, 0.f);

  // --- layer 2: gather applies BN+ReLU inline (reads h1pre; no separate BN pass) ---
  k_gatherb<true><<<gablocks, 256, 0, stream>>>(hpre_b, slots, offs, meanb, N,
                                                sum1, sq1, g1, be1, invN);

  // fused layer-2 + skip GEMM; self-half BN applied during A-staging
  k_mfma<true><<<gpersist, 256, 0, stream>>>(hpre_b, meanb, Wb2, Wb3, b2, b_skip,
                                             h2pre, skip_b, sum2, sq2, sum3, sq3,
                                             N, NT, sum1, sq1, g1, be1, invN);

  k_final<<<4096, 256, 0, stream>>>(h2pre, skip_b, out,
                                    sum2, sq2, g2, be2, sum3, sq3, g3, be3, invN, n4);
}